// Round 15
// baseline (517.973 us; speedup 1.0000x reference)
//
#include <hip/hip_runtime.h>
#include <hip/hip_bf16.h>
#include <hip/hip_cooperative_groups.h>

namespace cg = cooperative_groups;

#define N_NODES 10000
#define N_EDGES 640000
#define IN_DIM  128
#define HID_DIM 256
#define OUT_DIM 128

#define MAXDEG     128     // deg ~ Binom(640k,1e-4): mean 64, P(>128) ~ 1e-11
#define NCHUNK     64
#define CEDGES     (N_EDGES / NCHUNK)        // 10000 edges per chunk
#define NPART      8
#define PART_NODES (N_NODES / NPART)         // 1250
#define HSTRIDE    10240                     // padded node stride in HO
#define SH_STR     264                       // LDS h-slab row stride (ushorts)

#define PREP_X   (N_NODES * IN_DIM)
#define PREP_W1  (HID_DIM * (2 * IN_DIM))
#define PREP_W2  (OUT_DIM * HID_DIM)
#define PREP_TOTAL (PREP_X + PREP_W1 + 2 * PREP_W2)
#define PREP_BLOCKS (PREP_TOTAL / 256)       // 5512 exactly
#define HIST_UNITS  (NCHUNK * NPART)         // 512
#define GATHER_UNITS (N_NODES / 4)           // 2500 (4 nodes per 256-thr block)

typedef __attribute__((ext_vector_type(8))) short short8;
typedef __attribute__((ext_vector_type(4))) float float4v;
typedef unsigned short ushort_t;
typedef unsigned int uint_t;

struct Ctx {
    const float* x; const int* ei;
    const float* W1_l; const float* b1; const float* W1_r;
    const float* W2_l; const float* b2; const float* W2_r;
    float* out;
    int* HO; int* deg; ushort_t* esrc2;
    ushort_t* xb; ushort_t* aggb; ushort_t* w1t; ushort_t* w2tl; ushort_t* w2tr;
    float* Rf;
};

__device__ inline ushort_t f2bf(float f) {
    uint_t u = __float_as_uint(f);
    u += 0x7fffu + ((u >> 16) & 1u);
    return (ushort_t)(u >> 16);
}
__device__ inline float bf_lo(uint_t u) { return __uint_as_float(u << 16); }
__device__ inline float bf_hi(uint_t u) { return __uint_as_float(u & 0xffff0000u); }

// ---------------------------------------------------------------------------
// Phase bodies (verbatim R13 logic), shared by mega-kernel and fallbacks.
// ---------------------------------------------------------------------------
__device__ __forceinline__ void phase_prep_hist(const Ctx& c, int vb, int tid, int* s_i) {
    const int* dst = c.ei + N_EDGES;
    if (vb < PREP_BLOCKS) {
        int i = vb * 256 + tid;
        if (i < PREP_X) {
            c.xb[i] = f2bf(c.x[i]);
        } else if (i < PREP_X + PREP_W1) {
            int j = i - PREP_X;
            int n = j >> 8, k = j & 255;         // w1t[n][k], n in [0,256)
            float v = (k < 128) ? c.W1_l[k * HID_DIM + n]
                                : c.W1_r[(k - 128) * HID_DIM + n];
            c.w1t[j] = f2bf(v);
        } else if (i < PREP_X + PREP_W1 + PREP_W2) {
            int j = i - (PREP_X + PREP_W1);
            int n = j >> 8, k = j & 255;
            c.w2tl[j] = f2bf(c.W2_l[k * OUT_DIM + n]);
        } else {
            int j = i - (PREP_X + PREP_W1 + PREP_W2);
            int n = j >> 8, k = j & 255;
            c.w2tr[j] = f2bf(c.W2_r[k * OUT_DIM + n]);
        }
        return;
    }
    const int hb_   = vb - PREP_BLOCKS;
    const int part  = hb_ & (NPART - 1);
    const int chunk = hb_ >> 3;
    const int lo    = part * PART_NODES;
    __syncthreads();                              // protect s_i from prior unit
    for (int i = tid; i < PART_NODES; i += 256) s_i[i] = 0;
    __syncthreads();
    const int4* d4 = (const int4*)(dst + chunk * CEDGES);
    for (int i = tid; i < CEDGES / 4; i += 256) {
        int4 v = d4[i];
        int a;
        a = v.x - lo; if ((unsigned)a < (unsigned)PART_NODES) atomicAdd(&s_i[a], 1);
        a = v.y - lo; if ((unsigned)a < (unsigned)PART_NODES) atomicAdd(&s_i[a], 1);
        a = v.z - lo; if ((unsigned)a < (unsigned)PART_NODES) atomicAdd(&s_i[a], 1);
        a = v.w - lo; if ((unsigned)a < (unsigned)PART_NODES) atomicAdd(&s_i[a], 1);
    }
    __syncthreads();
    int* row = c.HO + chunk * HSTRIDE + lo;
    for (int i = tid; i < PART_NODES; i += 256) row[i] = s_i[i];
}

__device__ __forceinline__ void phase_scan(const Ctx& c, int vb, int tid) {
    int n = vb * 256 + tid;
    if (n >= N_NODES) return;
    int s = 0;
    for (int b = 0; b < NCHUNK; ++b) {
        int v = c.HO[b * HSTRIDE + n];
        c.HO[b * HSTRIDE + n] = s;
        s += v;
    }
    c.deg[n] = s;
}

__device__ __forceinline__ void phase_scatter(const Ctx& c, int vb, int tid, int* s_i) {
    const int* src = c.ei;
    const int* dst = c.ei + N_EDGES;
    const int part  = vb & (NPART - 1);
    const int chunk = vb >> 3;
    const int lo    = part * PART_NODES;
    __syncthreads();
    for (int i = tid; i < PART_NODES; i += 256)
        s_i[i] = c.HO[chunk * HSTRIDE + lo + i];
    __syncthreads();
    const int base = chunk * CEDGES;
    for (int e = base + tid; e < base + CEDGES; e += 256) {
        int d = dst[e] - lo;
        if ((unsigned)d < (unsigned)PART_NODES) {
            int pos = atomicAdd(&s_i[d], 1);      // LDS atomic, low contention
            if (pos < MAXDEG) c.esrc2[(lo + d) * MAXDEG + pos] = (ushort_t)src[e];
        }
    }
}

// Wave-cooperative gather: 16 lanes x uint4 per 256B row, 4 slot groups,
// 2-deep unroll. After reduce, g==0 lanes hold 8 column sums.
__device__ __forceinline__ void gather_sum(const uint4* __restrict__ f,
                                           const ushort_t* __restrict__ idx,
                                           int deg, int g, int cc, float* a) {
    float a0=0,a1=0,a2=0,a3=0,a4=0,a5=0,a6=0,a7=0;
    int e = g;
    for (; e + 4 < deg; e += 8) {
        uint4 u = f[(int)idx[e] * 16 + cc];
        uint4 v = f[(int)idx[e + 4] * 16 + cc];
        a0 += bf_lo(u.x) + bf_lo(v.x); a1 += bf_hi(u.x) + bf_hi(v.x);
        a2 += bf_lo(u.y) + bf_lo(v.y); a3 += bf_hi(u.y) + bf_hi(v.y);
        a4 += bf_lo(u.z) + bf_lo(v.z); a5 += bf_hi(u.z) + bf_hi(v.z);
        a6 += bf_lo(u.w) + bf_lo(v.w); a7 += bf_hi(u.w) + bf_hi(v.w);
    }
    if (e < deg) {
        uint4 u = f[(int)idx[e] * 16 + cc];
        a0 += bf_lo(u.x); a1 += bf_hi(u.x);
        a2 += bf_lo(u.y); a3 += bf_hi(u.y);
        a4 += bf_lo(u.z); a5 += bf_hi(u.z);
        a6 += bf_lo(u.w); a7 += bf_hi(u.w);
    }
#pragma unroll
    for (int off = 32; off >= 16; off >>= 1) {
        a0 += __shfl_down(a0, off); a1 += __shfl_down(a1, off);
        a2 += __shfl_down(a2, off); a3 += __shfl_down(a3, off);
        a4 += __shfl_down(a4, off); a5 += __shfl_down(a5, off);
        a6 += __shfl_down(a6, off); a7 += __shfl_down(a7, off);
    }
    a[0]=a0; a[1]=a1; a[2]=a2; a[3]=a3; a[4]=a4; a[5]=a5; a[6]=a6; a[7]=a7;
}

__device__ __forceinline__ void phase_gather1(const Ctx& c, int vb, int tid) {
    const uint4* f = (const uint4*)c.xb;
    const int w = tid >> 6, l = tid & 63;
    const int g = l >> 4, cc = l & 15;
    const int n = vb * 4 + w;
    const int dg = min(c.deg[n], MAXDEG);
    float a[8];
    gather_sum(f, c.esrc2 + n * MAXDEG, dg, g, cc, a);
    if (g == 0) {
        const float dinv = (dg > 0) ? 1.0f / (float)dg : 0.0f;
        uint4 o;
        o.x = (uint_t)f2bf(a[0] * dinv) | ((uint_t)f2bf(a[1] * dinv) << 16);
        o.y = (uint_t)f2bf(a[2] * dinv) | ((uint_t)f2bf(a[3] * dinv) << 16);
        o.z = (uint_t)f2bf(a[4] * dinv) | ((uint_t)f2bf(a[5] * dinv) << 16);
        o.w = (uint_t)f2bf(a[6] * dinv) | ((uint_t)f2bf(a[7] * dinv) << 16);
        ((uint4*)c.aggb)[n * 16 + cc] = o;
    }
}

__device__ __forceinline__ void phase_mfma(const Ctx& c, int vb, int tid, ushort_t* s_h) {
    ushort_t* Pb = c.aggb;                   // alias: aggb dead after phase A reads
    const int wrow = vb * 16;
    const int w = tid >> 6, l = tid & 63;
    const int m = l & 15, q = l >> 4;
    __syncthreads();                          // protect arena from prior unit

    // Phase A: h cols [w*64,+64) = relu([agg|x] @ [W1_l;W1_r] + b1) -> LDS
    float4v acc[4];
#pragma unroll
    for (int t = 0; t < 4; ++t) acc[t] = (float4v){0.f, 0.f, 0.f, 0.f};
    const ushort_t* arow_a = c.aggb + (wrow + m) * IN_DIM + q * 8;
    const ushort_t* arow_x = c.xb   + (wrow + m) * IN_DIM + q * 8;
    const ushort_t* bbase  = c.w1t + (w * 64 + m) * 256 + q * 8;
#pragma unroll
    for (int s = 0; s < 8; ++s) {
        short8 a = (s < 4) ? *(const short8*)(arow_a + s * 32)
                           : *(const short8*)(arow_x + (s - 4) * 32);
#pragma unroll
        for (int t = 0; t < 4; ++t) {
            short8 b = *(const short8*)(bbase + (t * 16) * 256 + s * 32);
            acc[t] = __builtin_amdgcn_mfma_f32_16x16x32_bf16(a, b, acc[t], 0, 0, 0);
        }
    }
#pragma unroll
    for (int t = 0; t < 4; ++t) {
        int col = w * 64 + t * 16 + m;
        float bv = c.b1[col];
#pragma unroll
        for (int r = 0; r < 4; ++r) {
            float v = fmaxf(acc[t][r] + bv, 0.0f);
            s_h[(q * 4 + r) * SH_STR + col] = f2bf(v);
        }
    }
    __syncthreads();

    // Phase B: wave (w>>1) -> {P bf16, R f32}, col-half (w&1)*64, A from LDS
    const int which = w >> 1;
    const int colb  = (w & 1) * 64;
    const ushort_t* wt = which ? c.w2tr : c.w2tl;
    float4v acc2[4];
#pragma unroll
    for (int t = 0; t < 4; ++t) acc2[t] = (float4v){0.f, 0.f, 0.f, 0.f};
    const ushort_t* abase  = s_h + m * SH_STR + q * 8;
    const ushort_t* bbase2 = wt + (colb + m) * 256 + q * 8;
#pragma unroll
    for (int s = 0; s < 8; ++s) {
        short8 a = *(const short8*)(abase + s * 32);
#pragma unroll
        for (int t = 0; t < 4; ++t) {
            short8 b = *(const short8*)(bbase2 + (t * 16) * 256 + s * 32);
            acc2[t] = __builtin_amdgcn_mfma_f32_16x16x32_bf16(a, b, acc2[t], 0, 0, 0);
        }
    }
    if (which == 0) {
#pragma unroll
        for (int t = 0; t < 4; ++t) {
            int col = colb + t * 16 + m;
#pragma unroll
            for (int r = 0; r < 4; ++r)
                Pb[(wrow + q * 4 + r) * OUT_DIM + col] = f2bf(acc2[t][r]);
        }
    } else {
#pragma unroll
        for (int t = 0; t < 4; ++t) {
            int col = colb + t * 16 + m;
#pragma unroll
            for (int r = 0; r < 4; ++r)
                c.Rf[(wrow + q * 4 + r) * OUT_DIM + col] = acc2[t][r];
        }
    }
}

__device__ __forceinline__ void phase_gather2(const Ctx& c, int vb, int tid) {
    const uint4* f = (const uint4*)c.aggb;   // Pb alias
    const int w = tid >> 6, l = tid & 63;
    const int g = l >> 4, cc = l & 15;
    const int n = vb * 4 + w;
    const int dg = min(c.deg[n], MAXDEG);
    float a[8];
    gather_sum(f, c.esrc2 + n * MAXDEG, dg, g, cc, a);
    if (g == 0) {
        const float dinv = (dg > 0) ? 1.0f / (float)dg : 0.0f;
        const int base = n * OUT_DIM + cc * 8;
        float4 r0 = *(const float4*)(c.Rf + base);
        float4 r1 = *(const float4*)(c.Rf + base + 4);
        float4 o0, o1;
        o0.x = a[0] * dinv + r0.x + c.b2[cc * 8 + 0];
        o0.y = a[1] * dinv + r0.y + c.b2[cc * 8 + 1];
        o0.z = a[2] * dinv + r0.z + c.b2[cc * 8 + 2];
        o0.w = a[3] * dinv + r0.w + c.b2[cc * 8 + 3];
        o1.x = a[4] * dinv + r1.x + c.b2[cc * 8 + 4];
        o1.y = a[5] * dinv + r1.y + c.b2[cc * 8 + 5];
        o1.z = a[6] * dinv + r1.z + c.b2[cc * 8 + 6];
        o1.w = a[7] * dinv + r1.w + c.b2[cc * 8 + 7];
        *(float4*)(c.out + base)     = o0;
        *(float4*)(c.out + base + 4) = o1;
    }
}

// ---------------------------------------------------------------------------
// Cooperative mega-kernel (grid sized by occupancy query at launch).
// ---------------------------------------------------------------------------
__global__ void mega_kernel(Ctx c) {
    cg::grid_group grid = cg::this_grid();
    __shared__ __align__(16) unsigned char smem[16 * SH_STR * 2];   // 8448 B arena
    const int tid = threadIdx.x;
    const int stride = gridDim.x;

    for (int vb = blockIdx.x; vb < PREP_BLOCKS + HIST_UNITS; vb += stride)
        phase_prep_hist(c, vb, tid, (int*)smem);
    grid.sync();
    for (int vb = blockIdx.x; vb < 40; vb += stride) phase_scan(c, vb, tid);
    grid.sync();
    for (int vb = blockIdx.x; vb < HIST_UNITS; vb += stride)
        phase_scatter(c, vb, tid, (int*)smem);
    grid.sync();
    for (int vb = blockIdx.x; vb < GATHER_UNITS; vb += stride) phase_gather1(c, vb, tid);
    grid.sync();
    for (int vb = blockIdx.x; vb < 625; vb += stride)
        phase_mfma(c, vb, tid, (ushort_t*)smem);
    grid.sync();
    for (int vb = blockIdx.x; vb < GATHER_UNITS; vb += stride) phase_gather2(c, vb, tid);
}

// ---------------------------------------------------------------------------
// Fallback kernels (same phase bodies, 6 regular dispatches).
// ---------------------------------------------------------------------------
__global__ void k_prep_hist(Ctx c) {
    __shared__ __align__(16) int s_i[PART_NODES];
    phase_prep_hist(c, blockIdx.x, threadIdx.x, s_i);
}
__global__ void k_scan(Ctx c)    { phase_scan(c, blockIdx.x, threadIdx.x); }
__global__ void k_scatter(Ctx c) {
    __shared__ __align__(16) int s_i[PART_NODES];
    phase_scatter(c, blockIdx.x, threadIdx.x, s_i);
}
__global__ void k_gather1(Ctx c) { phase_gather1(c, blockIdx.x, threadIdx.x); }
__global__ void k_mfma(Ctx c) {
    __shared__ __align__(16) ushort_t s_h[16 * SH_STR];
    phase_mfma(c, blockIdx.x, threadIdx.x, s_h);
}
__global__ void k_gather2(Ctx c) { phase_gather2(c, blockIdx.x, threadIdx.x); }

// ---------------------------------------------------------------------------
// Launch: occupancy-sized cooperative, fallback to 6 dispatches on failure.
// ---------------------------------------------------------------------------
extern "C" void kernel_launch(void* const* d_in, const int* in_sizes, int n_in,
                              void* d_out, int out_size, void* d_ws, size_t ws_size,
                              hipStream_t stream) {
    // ---- workspace layout (int units) ----
    int* ip = (int*)d_ws;
    int*      HO    = ip;                           // 655,360 ints
    int*      deg   = ip + 655360;                  // 10,240
    ushort_t* esrc2 = (ushort_t*)(ip + 665600);     // 1,280,000 ushorts
    ushort_t* ub    = (ushort_t*)(ip + 1305600);

    Ctx c;
    c.x    = (const float*)d_in[0];
    c.ei   = (const int*)  d_in[1];
    c.W1_l = (const float*)d_in[2];
    c.b1   = (const float*)d_in[3];
    c.W1_r = (const float*)d_in[4];
    c.W2_l = (const float*)d_in[5];
    c.b2   = (const float*)d_in[6];
    c.W2_r = (const float*)d_in[7];
    c.out  = (float*)d_out;
    c.HO = HO; c.deg = deg; c.esrc2 = esrc2;
    c.xb   = ub;                 // 1,280,000
    c.aggb = ub + 1280000;       // 1,280,000 (aliased as Pb)
    c.w1t  = ub + 2560000;       //    65,536
    c.w2tl = ub + 2625536;       //    32,768
    c.w2tr = ub + 2658304;       //    32,768 -> ends 2,691,072
    c.Rf   = (float*)(ub + 2691072);   // 1,280,000 floats

    int nb = 0;
    hipError_t qe = hipOccupancyMaxActiveBlocksPerMultiprocessor(
        &nb, (const void*)mega_kernel, 256, 0);
    hipError_t le = hipErrorUnknown;
    if (qe == hipSuccess && nb >= 1) {
        int grid = nb * 256;               // 256 CUs on MI355X
        if (grid > 2048) grid = 2048;
        void* args[] = { (void*)&c };
        le = hipLaunchCooperativeKernel((const void*)mega_kernel,
                                        dim3(grid), dim3(256), args, 0, stream);
    }
    if (le != hipSuccess) {
        k_prep_hist<<<PREP_BLOCKS + HIST_UNITS, 256, 0, stream>>>(c);
        k_scan<<<40, 256, 0, stream>>>(c);
        k_scatter<<<HIST_UNITS, 256, 0, stream>>>(c);
        k_gather1<<<GATHER_UNITS, 256, 0, stream>>>(c);
        k_mfma<<<625, 256, 0, stream>>>(c);
        k_gather2<<<GATHER_UNITS, 256, 0, stream>>>(c);
    }
}

// Round 16
// 166.653 us; speedup vs baseline: 3.1081x; 3.1081x over previous
//
#include <hip/hip_runtime.h>
#include <hip/hip_bf16.h>

#define N_NODES 10000
#define N_EDGES 640000
#define IN_DIM  128
#define HID_DIM 256
#define OUT_DIM 128

#define MAXDEG     128     // deg ~ Binom(640k,1e-4): mean 64, P(>128) ~ 1e-11
#define NCHUNK     64
#define CEDGES     (N_EDGES / NCHUNK)        // 10000 edges per chunk
#define NPART      8
#define PART_NODES (N_NODES / NPART)         // 1250
#define HSTRIDE    10240                     // padded node stride in HO

typedef __attribute__((ext_vector_type(8))) short short8;
typedef __attribute__((ext_vector_type(4))) float float4v;
typedef unsigned short ushort_t;
typedef unsigned int uint_t;

__device__ inline ushort_t f2bf(float f) {
    uint_t u = __float_as_uint(f);
    u += 0x7fffu + ((u >> 16) & 1u);
    return (ushort_t)(u >> 16);
}
__device__ inline float bf_lo(uint_t u) { return __uint_as_float(u << 16); }
__device__ inline float bf_hi(uint_t u) { return __uint_as_float(u & 0xffff0000u); }

// ---------------------------------------------------------------------------
// Fused prep + windowed hist (independent work, one dispatch).
// ---------------------------------------------------------------------------
#define PREP_X   (N_NODES * IN_DIM)
#define PREP_W1  (HID_DIM * (2 * IN_DIM))
#define PREP_W2  (OUT_DIM * HID_DIM)
#define PREP_TOTAL (PREP_X + PREP_W1 + 2 * PREP_W2)
#define PREP_BLOCKS (PREP_TOTAL / 256)       // 5512 exactly

__global__ void prep_hist_kernel(const float* __restrict__ x,
                                 const float* __restrict__ W1_l, const float* __restrict__ W1_r,
                                 const float* __restrict__ W2_l, const float* __restrict__ W2_r,
                                 ushort_t* __restrict__ xb,  ushort_t* __restrict__ w1t,
                                 ushort_t* __restrict__ w2tl, ushort_t* __restrict__ w2tr,
                                 const int* __restrict__ dst, int* __restrict__ HO) {
    __shared__ int h[PART_NODES];
    const int bid = blockIdx.x;
    const int tid = threadIdx.x;
    if (bid < PREP_BLOCKS) {
        int i = bid * 256 + tid;
        if (i < PREP_X) {
            xb[i] = f2bf(x[i]);
        } else if (i < PREP_X + PREP_W1) {
            int j = i - PREP_X;
            int n = j >> 8, k = j & 255;        // w1t[n][k], n in [0,256)
            float v = (k < 128) ? W1_l[k * HID_DIM + n] : W1_r[(k - 128) * HID_DIM + n];
            w1t[j] = f2bf(v);
        } else if (i < PREP_X + PREP_W1 + PREP_W2) {
            int j = i - (PREP_X + PREP_W1);
            int n = j >> 8, k = j & 255;
            w2tl[j] = f2bf(W2_l[k * OUT_DIM + n]);
        } else {
            int j = i - (PREP_X + PREP_W1 + PREP_W2);
            int n = j >> 8, k = j & 255;
            w2tr[j] = f2bf(W2_r[k * OUT_DIM + n]);
        }
        return;
    }
    const int hb_   = bid - PREP_BLOCKS;
    const int part  = hb_ & (NPART - 1);
    const int chunk = hb_ >> 3;
    const int lo    = part * PART_NODES;
    for (int i = tid; i < PART_NODES; i += 256) h[i] = 0;
    __syncthreads();
    const int4* d4 = (const int4*)(dst + chunk * CEDGES);
    for (int i = tid; i < CEDGES / 4; i += 256) {
        int4 v = d4[i];
        int a;
        a = v.x - lo; if ((unsigned)a < (unsigned)PART_NODES) atomicAdd(&h[a], 1);
        a = v.y - lo; if ((unsigned)a < (unsigned)PART_NODES) atomicAdd(&h[a], 1);
        a = v.z - lo; if ((unsigned)a < (unsigned)PART_NODES) atomicAdd(&h[a], 1);
        a = v.w - lo; if ((unsigned)a < (unsigned)PART_NODES) atomicAdd(&h[a], 1);
    }
    __syncthreads();
    int* row = HO + chunk * HSTRIDE + lo;
    for (int i = tid; i < PART_NODES; i += 256) row[i] = h[i];
}

// ---------------------------------------------------------------------------
// CSR phase B: thread n converts column n of HO to exclusive per-chunk
// offsets (coalesced across n) and emits deg[n].
// ---------------------------------------------------------------------------
__global__ void scan_kernel(int* __restrict__ HO, int* __restrict__ deg) {
    int n = blockIdx.x * blockDim.x + threadIdx.x;
    if (n >= N_NODES) return;
    int s = 0;
    for (int b = 0; b < NCHUNK; ++b) {
        int v = HO[b * HSTRIDE + n];
        HO[b * HSTRIDE + n] = s;
        s += v;
    }
    deg[n] = s;
}

// ---------------------------------------------------------------------------
// CSR phase C: scatter with LDS cursors (slots pre-reserved by the scan —
// no global atomics). Block (chunk, part); plain byte-disjoint 2B stores.
// ---------------------------------------------------------------------------
__global__ void scatter_kernel(const int* __restrict__ src, const int* __restrict__ dst,
                               const int* __restrict__ HO, ushort_t* __restrict__ esrc2) {
    __shared__ int cur[PART_NODES];
    const int part  = blockIdx.x & (NPART - 1);
    const int chunk = blockIdx.x >> 3;
    const int lo    = part * PART_NODES;
    const int tid   = threadIdx.x;
    for (int i = tid; i < PART_NODES; i += 256)
        cur[i] = HO[chunk * HSTRIDE + lo + i];
    __syncthreads();
    const int base = chunk * CEDGES;
    for (int e = base + tid; e < base + CEDGES; e += 256) {
        int d = dst[e] - lo;
        if ((unsigned)d < (unsigned)PART_NODES) {
            int pos = atomicAdd(&cur[d], 1);          // LDS atomic, low contention
            if (pos < MAXDEG) esrc2[(lo + d) * MAXDEG + pos] = (ushort_t)src[e];
        }
    }
}

// ---------------------------------------------------------------------------
// Gather-mean over bf16 rows. One 64-thread block per node. 16 lanes x uint4
// cover a 256 B row (stride 16); 4 slot groups x 2-deep unroll.
// ---------------------------------------------------------------------------
__global__ void gather_mean_bf16(const ushort_t* __restrict__ feat,
                                 const int* __restrict__ degp,
                                 const ushort_t* __restrict__ esrc2,
                                 ushort_t* __restrict__ out) {
    const uint4* f = (const uint4*)feat;          // 16 uint4 per row
    const int n = blockIdx.x;
    const int g = threadIdx.x >> 4;               // slot group 0..3
    const int c = threadIdx.x & 15;               // 16B column 0..15
    const int deg = min(degp[n], MAXDEG);
    const ushort_t* idx = esrc2 + n * MAXDEG;

    float a0=0,a1=0,a2=0,a3=0,a4=0,a5=0,a6=0,a7=0;
    int e = g;
    for (; e + 4 < deg; e += 8) {                 // 2 independent rows in flight
        uint4 u = f[(int)idx[e] * 16 + c];
        uint4 v = f[(int)idx[e + 4] * 16 + c];
        a0 += bf_lo(u.x) + bf_lo(v.x); a1 += bf_hi(u.x) + bf_hi(v.x);
        a2 += bf_lo(u.y) + bf_lo(v.y); a3 += bf_hi(u.y) + bf_hi(v.y);
        a4 += bf_lo(u.z) + bf_lo(v.z); a5 += bf_hi(u.z) + bf_hi(v.z);
        a6 += bf_lo(u.w) + bf_lo(v.w); a7 += bf_hi(u.w) + bf_hi(v.w);
    }
    if (e < deg) {
        uint4 u = f[(int)idx[e] * 16 + c];
        a0 += bf_lo(u.x); a1 += bf_hi(u.x);
        a2 += bf_lo(u.y); a3 += bf_hi(u.y);
        a4 += bf_lo(u.z); a5 += bf_hi(u.z);
        a6 += bf_lo(u.w); a7 += bf_hi(u.w);
    }
#pragma unroll
    for (int off = 32; off >= 16; off >>= 1) {
        a0 += __shfl_down(a0, off); a1 += __shfl_down(a1, off);
        a2 += __shfl_down(a2, off); a3 += __shfl_down(a3, off);
        a4 += __shfl_down(a4, off); a5 += __shfl_down(a5, off);
        a6 += __shfl_down(a6, off); a7 += __shfl_down(a7, off);
    }
    if (g == 0) {
        const float dinv = (deg > 0) ? 1.0f / (float)deg : 0.0f;
        uint4 o;
        o.x = (uint_t)f2bf(a0 * dinv) | ((uint_t)f2bf(a1 * dinv) << 16);
        o.y = (uint_t)f2bf(a2 * dinv) | ((uint_t)f2bf(a3 * dinv) << 16);
        o.z = (uint_t)f2bf(a4 * dinv) | ((uint_t)f2bf(a5 * dinv) << 16);
        o.w = (uint_t)f2bf(a6 * dinv) | ((uint_t)f2bf(a7 * dinv) << 16);
        ((uint4*)out)[n * 16 + c] = o;
    }
}

// ---------------------------------------------------------------------------
// Final gather + epilogue: out[n][:] = mean_e P[esrc[e]][:] + R[n][:] + b2
// ---------------------------------------------------------------------------
__global__ void gather_final(const ushort_t* __restrict__ Pb,
                             const int* __restrict__ degp,
                             const ushort_t* __restrict__ esrc2,
                             const float* __restrict__ Rf,
                             const float* __restrict__ b2,
                             float* __restrict__ out) {
    const uint4* f = (const uint4*)Pb;            // 16 uint4 per row
    const int n = blockIdx.x;
    const int g = threadIdx.x >> 4;
    const int c = threadIdx.x & 15;
    const int deg = min(degp[n], MAXDEG);
    const ushort_t* idx = esrc2 + n * MAXDEG;

    float a0=0,a1=0,a2=0,a3=0,a4=0,a5=0,a6=0,a7=0;
    int e = g;
    for (; e + 4 < deg; e += 8) {
        uint4 u = f[(int)idx[e] * 16 + c];
        uint4 v = f[(int)idx[e + 4] * 16 + c];
        a0 += bf_lo(u.x) + bf_lo(v.x); a1 += bf_hi(u.x) + bf_hi(v.x);
        a2 += bf_lo(u.y) + bf_lo(v.y); a3 += bf_hi(u.y) + bf_hi(v.y);
        a4 += bf_lo(u.z) + bf_lo(v.z); a5 += bf_hi(u.z) + bf_hi(v.z);
        a6 += bf_lo(u.w) + bf_lo(v.w); a7 += bf_hi(u.w) + bf_hi(v.w);
    }
    if (e < deg) {
        uint4 u = f[(int)idx[e] * 16 + c];
        a0 += bf_lo(u.x); a1 += bf_hi(u.x);
        a2 += bf_lo(u.y); a3 += bf_hi(u.y);
        a4 += bf_lo(u.z); a5 += bf_hi(u.z);
        a6 += bf_lo(u.w); a7 += bf_hi(u.w);
    }
#pragma unroll
    for (int off = 32; off >= 16; off >>= 1) {
        a0 += __shfl_down(a0, off); a1 += __shfl_down(a1, off);
        a2 += __shfl_down(a2, off); a3 += __shfl_down(a3, off);
        a4 += __shfl_down(a4, off); a5 += __shfl_down(a5, off);
        a6 += __shfl_down(a6, off); a7 += __shfl_down(a7, off);
    }
    if (g == 0) {
        const float dinv = (deg > 0) ? 1.0f / (float)deg : 0.0f;
        const int base = n * OUT_DIM + c * 8;
        float4 r0 = *(const float4*)(Rf + base);
        float4 r1 = *(const float4*)(Rf + base + 4);
        float4 o0, o1;
        o0.x = a0 * dinv + r0.x + b2[c * 8 + 0];
        o0.y = a1 * dinv + r0.y + b2[c * 8 + 1];
        o0.z = a2 * dinv + r0.z + b2[c * 8 + 2];
        o0.w = a3 * dinv + r0.w + b2[c * 8 + 3];
        o1.x = a4 * dinv + r1.x + b2[c * 8 + 4];
        o1.y = a5 * dinv + r1.y + b2[c * 8 + 5];
        o1.z = a6 * dinv + r1.z + b2[c * 8 + 6];
        o1.w = a7 * dinv + r1.w + b2[c * 8 + 7];
        *(float4*)(out + base)     = o0;
        *(float4*)(out + base + 4) = o1;
    }
}

// ---------------------------------------------------------------------------
// MFMA layer 1: h = relu([agg|x] @ [W1_l;W1_r] + b1), bf16 out. K=256.
// A-frag: A[m=lane&15][k=q*8+j]; B-frag: Wt[n=lane&15][k=q*8+j];
// C/D: col=lane&15, row=q*4+reg (m89-verified layouts).
// ---------------------------------------------------------------------------
__global__ void mfma1_kernel(const ushort_t* __restrict__ aggb,
                             const ushort_t* __restrict__ xb,
                             const ushort_t* __restrict__ w1t,
                             const float* __restrict__ b1,
                             ushort_t* __restrict__ hb) {
    const int wrow = blockIdx.x * 16;
    const int half = blockIdx.y;
    const int l = threadIdx.x;
    const int m = l & 15, q = l >> 4;

    float4v acc[8];
#pragma unroll
    for (int t = 0; t < 8; ++t) acc[t] = (float4v){0.f, 0.f, 0.f, 0.f};

    const ushort_t* arow_a = aggb + (wrow + m) * IN_DIM + q * 8;
    const ushort_t* arow_x = xb   + (wrow + m) * IN_DIM + q * 8;
    const ushort_t* bbase  = w1t + (half * 128 + m) * 256 + q * 8;

#pragma unroll
    for (int s = 0; s < 8; ++s) {
        const ushort_t* ap = (s < 4) ? (arow_a + s * 32) : (arow_x + (s - 4) * 32);
        short8 a = *(const short8*)ap;
#pragma unroll
        for (int t = 0; t < 8; ++t) {
            short8 b = *(const short8*)(bbase + (t * 16) * 256 + s * 32);
            acc[t] = __builtin_amdgcn_mfma_f32_16x16x32_bf16(a, b, acc[t], 0, 0, 0);
        }
    }

#pragma unroll
    for (int t = 0; t < 8; ++t) {
        int col = half * 128 + t * 16 + m;
        float bv = b1[col];
#pragma unroll
        for (int r = 0; r < 4; ++r) {
            int row = wrow + q * 4 + r;
            float v = acc[t][r] + bv;
            v = fmaxf(v, 0.0f);
            hb[row * HID_DIM + col] = f2bf(v);
        }
    }
}

// ---------------------------------------------------------------------------
// MFMA layer 2: which=0 -> Pb = h @ W2_l (bf16); which=1 -> Rf = h @ W2_r (f32)
// ---------------------------------------------------------------------------
__global__ void mfma2_kernel(const ushort_t* __restrict__ hb,
                             const ushort_t* __restrict__ w2tl,
                             const ushort_t* __restrict__ w2tr,
                             ushort_t* __restrict__ Pb,
                             float* __restrict__ Rf) {
    const int wrow = blockIdx.x * 16;
    const int which = blockIdx.y;
    const ushort_t* wt = which ? w2tr : w2tl;
    const int l = threadIdx.x;
    const int m = l & 15, q = l >> 4;

    float4v acc[8];
#pragma unroll
    for (int t = 0; t < 8; ++t) acc[t] = (float4v){0.f, 0.f, 0.f, 0.f};

    const ushort_t* arow  = hb + (wrow + m) * HID_DIM + q * 8;
    const ushort_t* bbase = wt + m * 256 + q * 8;

#pragma unroll
    for (int s = 0; s < 8; ++s) {
        short8 a = *(const short8*)(arow + s * 32);
#pragma unroll
        for (int t = 0; t < 8; ++t) {
            short8 b = *(const short8*)(bbase + (t * 16) * 256 + s * 32);
            acc[t] = __builtin_amdgcn_mfma_f32_16x16x32_bf16(a, b, acc[t], 0, 0, 0);
        }
    }

    if (which == 0) {
#pragma unroll
        for (int t = 0; t < 8; ++t) {
            int col = t * 16 + m;
#pragma unroll
            for (int r = 0; r < 4; ++r)
                Pb[(wrow + q * 4 + r) * OUT_DIM + col] = f2bf(acc[t][r]);
        }
    } else {
#pragma unroll
        for (int t = 0; t < 8; ++t) {
            int col = t * 16 + m;
#pragma unroll
            for (int r = 0; r < 4; ++r)
                Rf[(wrow + q * 4 + r) * OUT_DIM + col] = acc[t][r];
        }
    }
}

// ---------------------------------------------------------------------------
// Launch (7 dispatches — best-measured configuration, R11)
// ---------------------------------------------------------------------------
extern "C" void kernel_launch(void* const* d_in, const int* in_sizes, int n_in,
                              void* d_out, int out_size, void* d_ws, size_t ws_size,
                              hipStream_t stream) {
    const float* x    = (const float*)d_in[0];
    const int*   ei   = (const int*)  d_in[1];
    const float* W1_l = (const float*)d_in[2];
    const float* b1   = (const float*)d_in[3];
    const float* W1_r = (const float*)d_in[4];
    const float* W2_l = (const float*)d_in[5];
    const float* b2   = (const float*)d_in[6];
    const float* W2_r = (const float*)d_in[7];
    float* out = (float*)d_out;

    const int* src = ei;
    const int* dst = ei + N_EDGES;

    // ---- workspace layout (int units) ----
    int* ip = (int*)d_ws;
    int*      HO    = ip;                           // 64*10240 = 655,360 ints
    int*      deg   = ip + 655360;                  // 10,240
    ushort_t* esrc2 = (ushort_t*)(ip + 665600);     // 1,280,000 ushorts
    ushort_t* ub    = (ushort_t*)(ip + 1305600);
    ushort_t* xb   = ub;               // 1,280,000
    ushort_t* aggb = ub + 1280000;     // 1,280,000 (reused as Pb after mfma1)
    ushort_t* w1t  = ub + 2560000;     //    65,536
    ushort_t* w2tl = ub + 2625536;     //    32,768
    ushort_t* w2tr = ub + 2658304;     //    32,768
    ushort_t* hb   = ub + 2691072;     // 2,560,000 -> ends 5,251,072
    ushort_t* Pb   = aggb;             // alias: aggb dead after mfma1
    float*    Rf   = (float*)(ub + 5251072);   // 1,280,000 floats

    // ---- fused prep + hist, then scan + scatter ----
    prep_hist_kernel<<<PREP_BLOCKS + NCHUNK * NPART, 256, 0, stream>>>(
        x, W1_l, W1_r, W2_l, W2_r, xb, w1t, w2tl, w2tr, dst, HO);
    scan_kernel<<<40, 256, 0, stream>>>(HO, deg);
    scatter_kernel<<<NCHUNK * NPART, 256, 0, stream>>>(src, dst, HO, esrc2);

    // ---- Layer 1 ----
    gather_mean_bf16<<<N_NODES, 64, 0, stream>>>(xb, deg, esrc2, aggb);
    mfma1_kernel<<<dim3(625, 2), 64, 0, stream>>>(aggb, xb, w1t, b1, hb);

    // ---- Layer 2 (projection trick + fused epilogue) ----
    mfma2_kernel<<<dim3(625, 2), 64, 0, stream>>>(hb, w2tl, w2tr, Pb, Rf);
    gather_final<<<N_NODES, 64, 0, stream>>>(Pb, deg, esrc2, Rf, b2, out);
}